// Round 1
// baseline (192383.508 us; speedup 1.0000x reference)
//
#include <hip/hip_runtime.h>
#include <hip/hip_bf16.h>
#include <cstdint>

// Problem dims (from reference)
#define B   128
#define T   80
#define VOCAB 10000
#define E   100
#define U   2048
#define G4  8192   // 4*U

// LSTM step tiling
#define ROWS 32    // batch rows per WG
#define UC   32    // units per WG (each with 4 gate columns)

__global__ __launch_bounds__(256)
void embed_kernel(const int* __restrict__ tokens, const float* __restrict__ emb,
                  float* __restrict__ X /* [T][B][E] */) {
    int idx = blockIdx.x * blockDim.x + threadIdx.x;
    if (idx >= T * B * E) return;
    int e = idx % E;
    int rem = idx / E;
    int b = rem % B;
    int t = rem / B;
    X[idx] = emb[(size_t)tokens[b * T + t] * E + e];
}

// Computes one LSTM layer step for a [ROWS x UC] tile of units:
//   z = x @ W + h_in @ Uw + bias   (gate cols: u, U+u, 2U+u, 3U+u)
//   c_new = sig(f)*c + sig(i)*tanh(g);  h_out = sig(o)*tanh(c_new)
__global__ __launch_bounds__(256)
void lstm_step(const float* __restrict__ x, int Ex,
               const float* __restrict__ h_in,
               const float* __restrict__ W,    // [Ex][G4]
               const float* __restrict__ Uw,   // [U][G4]
               const float* __restrict__ bias, // [G4]
               float* __restrict__ h_out,      // [B][U]
               float* __restrict__ c)          // [B][U] in/out (elementwise-owned)
{
    __shared__ float As[ROWS][65];  // KC=64 chunk, +1 pad against bank conflicts

    const int tid = threadIdx.x;
    const int tx  = tid & 15;   // col group (2 units each)
    const int ty  = tid >> 4;   // row group (rows ty and ty+16)
    const int uBase   = blockIdx.x * UC;
    const int rowBase = blockIdx.y * ROWS;
    const int cu0 = uBase + tx * 2;

    float acc[2][4][2];
#pragma unroll
    for (int r = 0; r < 2; ++r)
#pragma unroll
        for (int g = 0; g < 4; ++g)
#pragma unroll
            for (int cc = 0; cc < 2; ++cc) acc[r][g][cc] = 0.f;

    // two source phases: (x, W) with K=Ex, then (h_in, Uw) with K=U
#pragma unroll 1
    for (int src = 0; src < 2; ++src) {
        const float* A  = src ? h_in : x;
        const int    K  = src ? U : Ex;
        const float* Wt = src ? Uw : W;

        for (int k0 = 0; k0 < K; k0 += 64) {
            const int kc = min(64, K - k0);
            __syncthreads();
            // stage A tile [ROWS][kc] into LDS
            for (int i = tid; i < ROWS * 64; i += 256) {
                int r  = i >> 6;
                int kl = i & 63;
                As[r][kl] = (kl < kc) ? A[(size_t)(rowBase + r) * K + k0 + kl] : 0.f;
            }
            __syncthreads();

            const float* wrow = Wt + (size_t)k0 * G4;
            for (int kl = 0; kl < kc; ++kl) {
                float a0 = As[ty][kl];
                float a1 = As[ty + 16][kl];
                const float* wp = wrow + (size_t)kl * G4 + cu0;
#pragma unroll
                for (int g = 0; g < 4; ++g) {
                    float2 w = *(const float2*)(wp + g * U);
                    acc[0][g][0] += a0 * w.x;
                    acc[0][g][1] += a0 * w.y;
                    acc[1][g][0] += a1 * w.x;
                    acc[1][g][1] += a1 * w.y;
                }
            }
        }
    }

    // fused gates + state update
#pragma unroll
    for (int r = 0; r < 2; ++r) {
        const int row = rowBase + ty + r * 16;
#pragma unroll
        for (int cc = 0; cc < 2; ++cc) {
            const int u = cu0 + cc;
            float iv = acc[r][0][cc] + bias[u];
            float fv = acc[r][1][cc] + bias[U + u];
            float gv = acc[r][2][cc] + bias[2 * U + u];
            float ov = acc[r][3][cc] + bias[3 * U + u];
            float si = 1.f / (1.f + __expf(-iv));
            float sf = 1.f / (1.f + __expf(-fv));
            float so = 1.f / (1.f + __expf(-ov));
            float tg = tanhf(gv);
            float cn = sf * c[(size_t)row * U + u] + si * tg;
            c[(size_t)row * U + u] = cn;
            h_out[(size_t)row * U + u] = so * tanhf(cn);
        }
    }
}

// y = relu(h1 @ Wd + bd)  — tile: 128 rows x 16 cols per WG, grid = U/16
__global__ __launch_bounds__(256)
void head1(const float* __restrict__ h1, const float* __restrict__ Wd,
           const float* __restrict__ bd, float* __restrict__ y)
{
    __shared__ float hs[B][33];
    const int tid = threadIdx.x;
    const int tx = tid & 15;
    const int ty = tid >> 4;
    const int colBase = blockIdx.x * 16;

    float acc[8];
#pragma unroll
    for (int j = 0; j < 8; ++j) acc[j] = 0.f;

    for (int k0 = 0; k0 < U; k0 += 32) {
        __syncthreads();
        for (int i = tid; i < B * 32; i += 256) {
            int r = i >> 5, kl = i & 31;
            hs[r][kl] = h1[(size_t)r * U + k0 + kl];
        }
        __syncthreads();
        for (int kl = 0; kl < 32; ++kl) {
            float w = Wd[(size_t)(k0 + kl) * U + colBase + tx];
#pragma unroll
            for (int j = 0; j < 8; ++j)
                acc[j] += hs[ty + j * 16][kl] * w;
        }
    }
#pragma unroll
    for (int j = 0; j < 8; ++j) {
        int row = ty + j * 16;
        float v = acc[j] + bd[colBase + tx];
        y[(size_t)row * U + colBase + tx] = v > 0.f ? v : 0.f;
    }
}

// out[b] = sigmoid(y[b,:] @ Wo + bo)
__global__ __launch_bounds__(256)
void head2(const float* __restrict__ y, const float* __restrict__ Wo,
           const float* __restrict__ bo, float* __restrict__ out)
{
    __shared__ float red[256];
    const int b = blockIdx.x;
    const int tid = threadIdx.x;
    float s = 0.f;
    for (int u = tid; u < U; u += 256) s += y[(size_t)b * U + u] * Wo[u];
    red[tid] = s;
    __syncthreads();
    for (int off = 128; off > 0; off >>= 1) {
        if (tid < off) red[tid] += red[tid + off];
        __syncthreads();
    }
    if (tid == 0) out[b] = 1.f / (1.f + __expf(-(red[0] + bo[0])));
}

extern "C" void kernel_launch(void* const* d_in, const int* in_sizes, int n_in,
                              void* d_out, int out_size, void* d_ws, size_t ws_size,
                              hipStream_t stream) {
    const int*   tokens = (const int*)  d_in[0];
    const float* emb    = (const float*)d_in[1];
    const float* W0     = (const float*)d_in[2];
    const float* U0     = (const float*)d_in[3];
    const float* b0     = (const float*)d_in[4];
    const float* W1     = (const float*)d_in[5];
    const float* U1     = (const float*)d_in[6];
    const float* b1     = (const float*)d_in[7];
    const float* Wd     = (const float*)d_in[8];
    const float* bd     = (const float*)d_in[9];
    const float* Wo     = (const float*)d_in[10];
    const float* bo     = (const float*)d_in[11];
    float* out = (float*)d_out;

    float* ws  = (float*)d_ws;
    float* X   = ws;                    // T*B*E
    float* h0a = X + (size_t)T * B * E; // states: 6 contiguous B*U buffers + y
    float* h0b = h0a + (size_t)B * U;
    float* c0  = h0b + (size_t)B * U;
    float* h1a = c0  + (size_t)B * U;
    float* h1b = h1a + (size_t)B * U;
    float* c1  = h1b + (size_t)B * U;
    float* y   = c1  + (size_t)B * U;

    // zero all state buffers (h0a..c1) in one async memset
    hipMemsetAsync(h0a, 0, (size_t)6 * B * U * sizeof(float), stream);

    embed_kernel<<<(T * B * E + 255) / 256, 256, 0, stream>>>(tokens, emb, X);

    dim3 grid(U / UC, B / ROWS);  // (64, 4) = 256 WGs
    for (int t = 0; t < T; ++t) {
        const float* h0in  = (t & 1) ? h0b : h0a;
        float*       h0out = (t & 1) ? h0a : h0b;
        const float* h1in  = (t & 1) ? h1b : h1a;
        float*       h1out = (t & 1) ? h1a : h1b;
        lstm_step<<<grid, 256, 0, stream>>>(X + (size_t)t * B * E, E,
                                            h0in, W0, U0, b0, h0out, c0);
        lstm_step<<<grid, 256, 0, stream>>>(h0out, U,
                                            h1in, W1, U1, b1, h1out, c1);
    }
    const float* h1fin = h1a;  // t=79 (odd) writes the 'a' buffer

    head1<<<U / 16, 256, 0, stream>>>(h1fin, Wd, bd, y);
    head2<<<B, 256, 0, stream>>>(y, Wo, bo, out);
}

// Round 2
// 9902.270 us; speedup vs baseline: 19.4282x; 19.4282x over previous
//
#include <hip/hip_runtime.h>
#include <hip/hip_bf16.h>
#include <cstdint>

#define B_   128
#define T_   80
#define E_   100
#define EP_  128     // E padded to multiple of 32
#define U_   2048
#define G4_  8192

typedef __attribute__((ext_vector_type(8))) short bf16x8;
typedef __attribute__((ext_vector_type(4))) float f32x4;

__device__ __forceinline__ ushort f2bf(float x) {
    __hip_bfloat16 h = __float2bfloat16(x);
    return *reinterpret_cast<ushort*>(&h);
}

// ---------------- embedding -> padded bf16 X [T][B][EP] ----------------
__global__ __launch_bounds__(256)
void embed_bf16(const int* __restrict__ tokens, const float* __restrict__ emb,
                ushort* __restrict__ X) {
    int idx = blockIdx.x * 256 + threadIdx.x;
    if (idx >= T_ * B_ * EP_) return;
    int e = idx & (EP_ - 1);
    int b = (idx >> 7) & (B_ - 1);
    int t = idx >> 14;
    float v = 0.f;
    if (e < E_) v = emb[(size_t)tokens[b * T_ + t] * E_ + e];
    X[idx] = f2bf(v);
}

// ---------------- weight pack: fp32 [K][Ncols] -> bf16 MFMA-fragment layout
// out[(((ut*KB + i)*NG + g)*64 + lane)*8 + j] = W[k][g*U_ + ut*16 + (lane&15)]
//   with k = i*32 + (lane>>4)*8 + j   (zero-padded for k >= K)
__global__ __launch_bounds__(256)
void pack_w(const float* __restrict__ W, int K, int Ncols, int NG, int KB,
            ushort* __restrict__ out) {
    int gtid = blockIdx.x * 256 + threadIdx.x;
    int lane = gtid & 63;
    int rest = gtid >> 6;
    int g = rest % NG; rest /= NG;
    int i = rest % KB;
    int ut = rest / KB;
    if (ut >= U_ / 16) return;
    int col = g * U_ + ut * 16 + (lane & 15);
    int k0 = i * 32 + (lane >> 4) * 8;
    ushort v[8];
#pragma unroll
    for (int j = 0; j < 8; ++j) {
        int k = k0 + j;
        v[j] = f2bf(k < K ? W[(size_t)k * Ncols + col] : 0.f);
    }
    *reinterpret_cast<uint4*>(out + (size_t)gtid * 8) = *reinterpret_cast<const uint4*>(v);
}

// ---------------- fused LSTM step: z = A0@W0p + A1@W1p + bias; gate update
// grid = 256 WGs: blockIdx = mh*128 + ut. WG = 4 waves, wave g computes gate g
// for rows [mh*64, mh*64+64) x units [ut*16, ut*16+16).
__global__ __launch_bounds__(256)
void lstm_step_mfma(const ushort* __restrict__ A0, int lda0,
                    const ushort* __restrict__ Wp0, int kb0,
                    const ushort* __restrict__ A1, int lda1,
                    const ushort* __restrict__ Wp1, int kb1,
                    const float* __restrict__ bias,
                    float* __restrict__ c,
                    ushort* __restrict__ h_out) {
    const int lane = threadIdx.x & 63;
    const int g    = threadIdx.x >> 6;   // wave index = gate (i,f,g,o)
    const int ut   = blockIdx.x & 127;
    const int mh   = blockIdx.x >> 7;
    const int cl   = lane & 15;
    const int kl   = (lane >> 4) * 8;

    const ushort* a0p[4];
    const ushort* a1p[4];
#pragma unroll
    for (int mt = 0; mt < 4; ++mt) {
        int row = mh * 64 + mt * 16 + cl;
        a0p[mt] = A0 + (size_t)row * lda0 + kl;
        a1p[mt] = A1 + (size_t)row * lda1 + kl;
    }
    const ushort* wp0 = Wp0 + ((size_t)(ut * kb0) * 4 + g) * 512 + lane * 8;
    const ushort* wp1 = Wp1 + ((size_t)(ut * kb1) * 4 + g) * 512 + lane * 8;

    f32x4 acc[4];
#pragma unroll
    for (int mt = 0; mt < 4; ++mt) acc[mt] = f32x4{0.f, 0.f, 0.f, 0.f};

    auto LOAD = [&](int i, bf16x8* a, bf16x8& b) {
        if (i < kb0) {
            b = *reinterpret_cast<const bf16x8*>(wp0 + (size_t)i * 2048);
#pragma unroll
            for (int mt = 0; mt < 4; ++mt)
                a[mt] = *reinterpret_cast<const bf16x8*>(a0p[mt] + i * 32);
        } else {
            int ii = i - kb0;
            b = *reinterpret_cast<const bf16x8*>(wp1 + (size_t)ii * 2048);
#pragma unroll
            for (int mt = 0; mt < 4; ++mt)
                a[mt] = *reinterpret_cast<const bf16x8*>(a1p[mt] + ii * 32);
        }
    };

    const int KBt = kb0 + kb1;  // always even here (68 or 128)
    bf16x8 aA[4], bA, aB[4], bB;
    LOAD(0, aA, bA);
    for (int i = 0; i < KBt; i += 2) {
        LOAD(i + 1, aB, bB);
#pragma unroll
        for (int mt = 0; mt < 4; ++mt)
            acc[mt] = __builtin_amdgcn_mfma_f32_16x16x32_bf16(aA[mt], bA, acc[mt], 0, 0, 0);
        if (i + 2 < KBt) LOAD(i + 2, aA, bA);
#pragma unroll
        for (int mt = 0; mt < 4; ++mt)
            acc[mt] = __builtin_amdgcn_mfma_f32_16x16x32_bf16(aB[mt], bB, acc[mt], 0, 0, 0);
    }

    // gate exchange through LDS: zs[gate][row_local][unit_local]
    __shared__ float zs[4][64][16];
#pragma unroll
    for (int mt = 0; mt < 4; ++mt)
#pragma unroll
        for (int r = 0; r < 4; ++r)
            zs[g][mt * 16 + (lane >> 4) * 4 + r][cl] = acc[mt][r];
    __syncthreads();

    const int tid = threadIdx.x;
    const int lr  = tid >> 2;          // 0..63
    const int u4  = (tid & 3) * 4;     // 0,4,8,12
    const int grow = mh * 64 + lr;
    const int gu   = ut * 16 + u4;

    float4 zi = *reinterpret_cast<float4*>(&zs[0][lr][u4]);
    float4 zf = *reinterpret_cast<float4*>(&zs[1][lr][u4]);
    float4 zg = *reinterpret_cast<float4*>(&zs[2][lr][u4]);
    float4 zo = *reinterpret_cast<float4*>(&zs[3][lr][u4]);
    float4 cv = *reinterpret_cast<float4*>(&c[(size_t)grow * U_ + gu]);
    const float4 bi  = *reinterpret_cast<const float4*>(&bias[gu]);
    const float4 bfv = *reinterpret_cast<const float4*>(&bias[U_ + gu]);
    const float4 bgv = *reinterpret_cast<const float4*>(&bias[2 * U_ + gu]);
    const float4 bov = *reinterpret_cast<const float4*>(&bias[3 * U_ + gu]);

    float4 cn;
    ushort4 hv;
#define GATE(comp)                                                              \
    {                                                                           \
        float iv = zi.comp + bi.comp, fv = zf.comp + bfv.comp;                  \
        float gv = zg.comp + bgv.comp, ov = zo.comp + bov.comp;                 \
        float si = 1.f / (1.f + __expf(-iv));                                   \
        float sf = 1.f / (1.f + __expf(-fv));                                   \
        float so = 1.f / (1.f + __expf(-ov));                                   \
        float tg = tanhf(gv);                                                   \
        float cc = sf * cv.comp + si * tg;                                      \
        cn.comp = cc;                                                           \
        hv.comp = f2bf(so * tanhf(cc));                                         \
    }
    GATE(x) GATE(y) GATE(z) GATE(w)
#undef GATE

    *reinterpret_cast<float4*>(&c[(size_t)grow * U_ + gu]) = cn;
    *reinterpret_cast<ushort4*>(&h_out[(size_t)grow * U_ + gu]) = hv;
}

// ---------------- head: y = relu(h1 @ Wd + bd), MFMA, waves split K ----------
__global__ __launch_bounds__(256)
void head_mfma(const ushort* __restrict__ h1, const ushort* __restrict__ Wdp,
               const float* __restrict__ bd, float* __restrict__ y) {
    const int lane = threadIdx.x & 63;
    const int w    = threadIdx.x >> 6;  // k-split wave
    const int ut   = blockIdx.x & 127;
    const int mh   = blockIdx.x >> 7;
    const int cl   = lane & 15;
    const int kl   = (lane >> 4) * 8;

    const ushort* ap[4];
#pragma unroll
    for (int mt = 0; mt < 4; ++mt) {
        int row = mh * 64 + mt * 16 + cl;
        ap[mt] = h1 + (size_t)row * U_ + kl;
    }
    const ushort* wp = Wdp + (size_t)(ut * 64 + w * 16) * 512 + lane * 8;

    f32x4 acc[4];
#pragma unroll
    for (int mt = 0; mt < 4; ++mt) acc[mt] = f32x4{0.f, 0.f, 0.f, 0.f};

    auto LOADH = [&](int i, bf16x8* a, bf16x8& b) {
        b = *reinterpret_cast<const bf16x8*>(wp + (size_t)i * 512);
        int kb = w * 16 + i;
#pragma unroll
        for (int mt = 0; mt < 4; ++mt)
            a[mt] = *reinterpret_cast<const bf16x8*>(ap[mt] + kb * 32);
    };

    bf16x8 aA[4], bA, aB[4], bB;
    LOADH(0, aA, bA);
    for (int i = 0; i < 16; i += 2) {
        LOADH(i + 1, aB, bB);
#pragma unroll
        for (int mt = 0; mt < 4; ++mt)
            acc[mt] = __builtin_amdgcn_mfma_f32_16x16x32_bf16(aA[mt], bA, acc[mt], 0, 0, 0);
        if (i + 2 < 16) LOADH(i + 2, aA, bA);
#pragma unroll
        for (int mt = 0; mt < 4; ++mt)
            acc[mt] = __builtin_amdgcn_mfma_f32_16x16x32_bf16(aB[mt], bB, acc[mt], 0, 0, 0);
    }

    __shared__ float zs[4][64][16];
#pragma unroll
    for (int mt = 0; mt < 4; ++mt)
#pragma unroll
        for (int r = 0; r < 4; ++r)
            zs[w][mt * 16 + (lane >> 4) * 4 + r][cl] = acc[mt][r];
    __syncthreads();

    const int tid = threadIdx.x;
    const int lr  = tid >> 2;
    const int u4  = (tid & 3) * 4;
    const int grow = mh * 64 + lr;
    const int gu   = ut * 16 + u4;

    float4 s0 = *reinterpret_cast<float4*>(&zs[0][lr][u4]);
    float4 s1 = *reinterpret_cast<float4*>(&zs[1][lr][u4]);
    float4 s2 = *reinterpret_cast<float4*>(&zs[2][lr][u4]);
    float4 s3 = *reinterpret_cast<float4*>(&zs[3][lr][u4]);
    const float4 bb = *reinterpret_cast<const float4*>(&bd[gu]);
    float4 r;
    r.x = s0.x + s1.x + s2.x + s3.x + bb.x;
    r.y = s0.y + s1.y + s2.y + s3.y + bb.y;
    r.z = s0.z + s1.z + s2.z + s3.z + bb.z;
    r.w = s0.w + s1.w + s2.w + s3.w + bb.w;
    r.x = r.x > 0.f ? r.x : 0.f;
    r.y = r.y > 0.f ? r.y : 0.f;
    r.z = r.z > 0.f ? r.z : 0.f;
    r.w = r.w > 0.f ? r.w : 0.f;
    *reinterpret_cast<float4*>(&y[(size_t)grow * U_ + gu]) = r;
}

// ---------------- out[b] = sigmoid(y[b,:] @ Wo + bo) ----------------
__global__ __launch_bounds__(256)
void head2(const float* __restrict__ y, const float* __restrict__ Wo,
           const float* __restrict__ bo, float* __restrict__ out) {
    __shared__ float red[256];
    const int b = blockIdx.x;
    const int tid = threadIdx.x;
    float s = 0.f;
    for (int u = tid; u < U_; u += 256) s += y[(size_t)b * U_ + u] * Wo[u];
    red[tid] = s;
    __syncthreads();
    for (int off = 128; off > 0; off >>= 1) {
        if (tid < off) red[tid] += red[tid + off];
        __syncthreads();
    }
    if (tid == 0) out[b] = 1.f / (1.f + __expf(-(red[0] + bo[0])));
}

extern "C" void kernel_launch(void* const* d_in, const int* in_sizes, int n_in,
                              void* d_out, int out_size, void* d_ws, size_t ws_size,
                              hipStream_t stream) {
    const int*   tokens = (const int*)  d_in[0];
    const float* emb    = (const float*)d_in[1];
    const float* W0     = (const float*)d_in[2];
    const float* U0     = (const float*)d_in[3];
    const float* b0     = (const float*)d_in[4];
    const float* W1     = (const float*)d_in[5];
    const float* U1     = (const float*)d_in[6];
    const float* b1     = (const float*)d_in[7];
    const float* Wd     = (const float*)d_in[8];
    const float* bd     = (const float*)d_in[9];
    const float* Wo     = (const float*)d_in[10];
    const float* bo     = (const float*)d_in[11];

    // ws layout (bytes); requires ws_size >= ~120 MB
    char* base = (char*)d_ws;
    ushort* h0a = (ushort*)(base + 0);          //  512 KB
    ushort* h1a = (ushort*)(base + 524288);     //  512 KB
    float*  c0  = (float*) (base + 1048576);    // 1 MB
    float*  c1  = (float*) (base + 2097152);    // 1 MB
    ushort* h0b = (ushort*)(base + 3145728);
    ushort* h1b = (ushort*)(base + 3670016);
    float*  yb  = (float*) (base + 4194304);    // 1 MB
    ushort* Xbf = (ushort*)(base + 5242880);    // 2.5 MB
    ushort* W0p = (ushort*)(base + 7864320);    // 2 MB
    ushort* U0p = (ushort*)(base + 9961472);    // 32 MB
    ushort* W1p = (ushort*)(base + 43515904);   // 32 MB
    ushort* U1p = (ushort*)(base + 77070336);   // 32 MB
    ushort* Wdp = (ushort*)(base + 110624768);  // 8 MB

    // zero h0a, h1a, c0, c1 (contiguous 3 MB)
    hipMemsetAsync(d_ws, 0, 3145728, stream);

    embed_bf16<<<(T_ * B_ * EP_ + 255) / 256, 256, 0, stream>>>(tokens, emb, Xbf);
    pack_w<<<512,  256, 0, stream>>>(W0, E_, G4_, 4, 4,  W0p);
    pack_w<<<8192, 256, 0, stream>>>(U0, U_, G4_, 4, 64, U0p);
    pack_w<<<8192, 256, 0, stream>>>(W1, U_, G4_, 4, 64, W1p);
    pack_w<<<8192, 256, 0, stream>>>(U1, U_, G4_, 4, 64, U1p);
    pack_w<<<2048, 256, 0, stream>>>(Wd, U_, U_,  1, 64, Wdp);

    for (int t = 0; t < T_; ++t) {
        const ushort* h0in  = (t & 1) ? h0b : h0a;
        ushort*       h0out = (t & 1) ? h0a : h0b;
        const ushort* h1in  = (t & 1) ? h1b : h1a;
        ushort*       h1out = (t & 1) ? h1a : h1b;
        lstm_step_mfma<<<256, 256, 0, stream>>>(Xbf + (size_t)t * B_ * EP_, EP_, W0p, 4,
                                                h0in, U_, U0p, 64, b0, c0, h0out);
        lstm_step_mfma<<<256, 256, 0, stream>>>(h0out, U_, W1p, 64,
                                                h1in, U_, U1p, 64, b1, c1, h1out);
    }
    // t=79 (odd) wrote the 'a' buffers
    head_mfma<<<256, 256, 0, stream>>>(h1a, Wdp, bd, yb);
    head2<<<B_, 256, 0, stream>>>(yb, Wo, bo, (float*)d_out);
}

// Round 3
// 7905.524 us; speedup vs baseline: 24.3353x; 1.2526x over previous
//
#include <hip/hip_runtime.h>
#include <hip/hip_bf16.h>
#include <cstdint>

#define B_   128
#define T_   80
#define E_   100
#define EP_  128     // E padded to multiple of 32
#define U_   2048
#define G4_  8192

typedef __attribute__((ext_vector_type(8))) short bf16x8;
typedef __attribute__((ext_vector_type(4))) float f32x4;

__device__ __forceinline__ ushort f2bf(float x) {
    __hip_bfloat16 h = __float2bfloat16(x);
    return *reinterpret_cast<ushort*>(&h);
}

// ---------------- embedding -> padded bf16 X [T][B][EP] ----------------
__global__ __launch_bounds__(256)
void embed_bf16(const int* __restrict__ tokens, const float* __restrict__ emb,
                ushort* __restrict__ X) {
    int idx = blockIdx.x * 256 + threadIdx.x;
    if (idx >= T_ * B_ * EP_) return;
    int e = idx & (EP_ - 1);
    int b = (idx >> 7) & (B_ - 1);
    int t = idx >> 14;
    float v = 0.f;
    if (e < E_) v = emb[(size_t)tokens[b * T_ + t] * E_ + e];
    X[idx] = f2bf(v);
}

// ---------------- weight pack: fp32 [K][Ncols] -> bf16 MFMA-fragment layout
// out[(((ut*KB + i)*NG + g)*64 + lane)*8 + j] = W[k][g*U_ + ut*16 + (lane&15)]
//   with k = i*32 + (lane>>4)*8 + j   (zero-padded for k >= K)
__global__ __launch_bounds__(256)
void pack_w(const float* __restrict__ W, int K, int Ncols, int NG, int KB,
            ushort* __restrict__ out) {
    int gtid = blockIdx.x * 256 + threadIdx.x;
    int lane = gtid & 63;
    int rest = gtid >> 6;
    int g = rest % NG; rest /= NG;
    int i = rest % KB;
    int ut = rest / KB;
    if (ut >= U_ / 16) return;
    int col = g * U_ + ut * 16 + (lane & 15);
    int k0 = i * 32 + (lane >> 4) * 8;
    ushort v[8];
#pragma unroll
    for (int j = 0; j < 8; ++j) {
        int k = k0 + j;
        v[j] = f2bf(k < K ? W[(size_t)k * Ncols + col] : 0.f);
    }
    *reinterpret_cast<uint4*>(out + (size_t)gtid * 8) = *reinterpret_cast<const uint4*>(v);
}

// ---------------- fused LSTM step: z = A0@W0p + A1@W1p + bias; gate update
// grid = 256 WGs: blockIdx = mh*128 + ut. WG = 16 waves (1024 thr):
// wave w: gate g = w>>2, K-quarter kq = w&3. Each wave computes the 64x16
// (rows x units) tile of gate g over its K-quarter; partials summed in LDS.
__global__ __launch_bounds__(1024)
void lstm_step_mfma(const ushort* __restrict__ A0, int lda0,
                    const ushort* __restrict__ Wp0, int kb0,
                    const ushort* __restrict__ A1, int lda1,
                    const ushort* __restrict__ Wp1, int kb1,
                    const float* __restrict__ bias,
                    float* __restrict__ c,
                    ushort* __restrict__ h_out) {
    const int tid  = threadIdx.x;
    const int lane = tid & 63;
    const int w    = tid >> 6;     // 0..15
    const int g    = w >> 2;       // gate
    const int kq   = w & 3;        // K-quarter
    const int ut   = blockIdx.x & 127;
    const int mh   = blockIdx.x >> 7;
    const int cl   = lane & 15;
    const int kl   = (lane >> 4) * 8;

    const ushort* a0p[4];
    const ushort* a1p[4];
#pragma unroll
    for (int mt = 0; mt < 4; ++mt) {
        int row = mh * 64 + mt * 16 + cl;
        a0p[mt] = A0 + (size_t)row * lda0 + kl;
        a1p[mt] = A1 + (size_t)row * lda1 + kl;
    }
    const ushort* wp0 = Wp0 + ((size_t)(ut * kb0) * 4 + g) * 512 + lane * 8;
    const ushort* wp1 = Wp1 + ((size_t)(ut * kb1) * 4 + g) * 512 + lane * 8;

    f32x4 acc[4];
#pragma unroll
    for (int mt = 0; mt < 4; ++mt) acc[mt] = f32x4{0.f, 0.f, 0.f, 0.f};

    auto LOAD = [&](int i, bf16x8* a, bf16x8& b) {
        if (i < kb0) {
            b = *reinterpret_cast<const bf16x8*>(wp0 + (size_t)i * 2048);
#pragma unroll
            for (int mt = 0; mt < 4; ++mt)
                a[mt] = *reinterpret_cast<const bf16x8*>(a0p[mt] + i * 32);
        } else {
            int ii = i - kb0;
            b = *reinterpret_cast<const bf16x8*>(wp1 + (size_t)ii * 2048);
#pragma unroll
            for (int mt = 0; mt < 4; ++mt)
                a[mt] = *reinterpret_cast<const bf16x8*>(a1p[mt] + ii * 32);
        }
    };
#define MFMA4(aa, bb)                                                            \
    {                                                                            \
        _Pragma("unroll")                                                        \
        for (int mt = 0; mt < 4; ++mt)                                           \
            acc[mt] = __builtin_amdgcn_mfma_f32_16x16x32_bf16(aa[mt], bb, acc[mt], 0, 0, 0); \
    }

    const int KBt = kb0 + kb1;           // 68 or 128, divisible by 4
    const int KBq = KBt >> 2;
    const int beg = kq * KBq;
    const int end = beg + KBq;

    bf16x8 aA[4], bA, aB[4], bB;
    int i = beg;
    LOAD(i, aA, bA);
    for (; i + 1 < end; i += 2) {
        LOAD(i + 1, aB, bB);
        MFMA4(aA, bA);
        if (i + 2 < end) LOAD(i + 2, aA, bA);
        MFMA4(aB, bB);
    }
    if (i < end) MFMA4(aA, bA);
#undef MFMA4

    // partial-sum exchange: zs[w][row_local][unit_local]
    __shared__ float zs[16][64][16];   // 64 KB
#pragma unroll
    for (int mt = 0; mt < 4; ++mt)
#pragma unroll
        for (int r = 0; r < 4; ++r)
            zs[w][mt * 16 + (lane >> 4) * 4 + r][cl] = acc[mt][r];
    __syncthreads();

    // epilogue: one thread per (row, unit)
    const int lr = tid >> 4;       // 0..63
    const int u  = tid & 15;       // 0..15
    const int grow = mh * 64 + lr;
    const int gu   = ut * 16 + u;

    float zi = zs[0][lr][u] + zs[1][lr][u] + zs[2][lr][u] + zs[3][lr][u];
    float zf = zs[4][lr][u] + zs[5][lr][u] + zs[6][lr][u] + zs[7][lr][u];
    float zg = zs[8][lr][u] + zs[9][lr][u] + zs[10][lr][u] + zs[11][lr][u];
    float zo = zs[12][lr][u] + zs[13][lr][u] + zs[14][lr][u] + zs[15][lr][u];

    zi += bias[gu];
    zf += bias[U_ + gu];
    zg += bias[2 * U_ + gu];
    zo += bias[3 * U_ + gu];

    float si = 1.f / (1.f + __expf(-zi));
    float sf = 1.f / (1.f + __expf(-zf));
    float so = 1.f / (1.f + __expf(-zo));
    float tg = tanhf(zg);
    float cc = sf * c[(size_t)grow * U_ + gu] + si * tg;
    c[(size_t)grow * U_ + gu] = cc;
    h_out[(size_t)grow * U_ + gu] = f2bf(so * tanhf(cc));
}

// ---------------- head: y = relu(h1 @ Wd + bd), MFMA, waves split K ----------
__global__ __launch_bounds__(256)
void head_mfma(const ushort* __restrict__ h1, const ushort* __restrict__ Wdp,
               const float* __restrict__ bd, float* __restrict__ y) {
    const int lane = threadIdx.x & 63;
    const int w    = threadIdx.x >> 6;  // k-split wave
    const int ut   = blockIdx.x & 127;
    const int mh   = blockIdx.x >> 7;
    const int cl   = lane & 15;
    const int kl   = (lane >> 4) * 8;

    const ushort* ap[4];
#pragma unroll
    for (int mt = 0; mt < 4; ++mt) {
        int row = mh * 64 + mt * 16 + cl;
        ap[mt] = h1 + (size_t)row * U_ + kl;
    }
    const ushort* wp = Wdp + (size_t)(ut * 64 + w * 16) * 512 + lane * 8;

    f32x4 acc[4];
#pragma unroll
    for (int mt = 0; mt < 4; ++mt) acc[mt] = f32x4{0.f, 0.f, 0.f, 0.f};

    auto LOADH = [&](int i, bf16x8* a, bf16x8& b) {
        b = *reinterpret_cast<const bf16x8*>(wp + (size_t)i * 512);
        int kb = w * 16 + i;
#pragma unroll
        for (int mt = 0; mt < 4; ++mt)
            a[mt] = *reinterpret_cast<const bf16x8*>(ap[mt] + kb * 32);
    };

    bf16x8 aA[4], bA, aB[4], bB;
    LOADH(0, aA, bA);
    for (int i = 0; i < 16; i += 2) {
        LOADH(i + 1, aB, bB);
#pragma unroll
        for (int mt = 0; mt < 4; ++mt)
            acc[mt] = __builtin_amdgcn_mfma_f32_16x16x32_bf16(aA[mt], bA, acc[mt], 0, 0, 0);
        if (i + 2 < 16) LOADH(i + 2, aA, bA);
#pragma unroll
        for (int mt = 0; mt < 4; ++mt)
            acc[mt] = __builtin_amdgcn_mfma_f32_16x16x32_bf16(aB[mt], bB, acc[mt], 0, 0, 0);
    }

    __shared__ float zs[4][64][16];
#pragma unroll
    for (int mt = 0; mt < 4; ++mt)
#pragma unroll
        for (int r = 0; r < 4; ++r)
            zs[w][mt * 16 + (lane >> 4) * 4 + r][cl] = acc[mt][r];
    __syncthreads();

    const int tid = threadIdx.x;
    const int lr  = tid >> 2;
    const int u4  = (tid & 3) * 4;
    const int grow = mh * 64 + lr;
    const int gu   = ut * 16 + u4;

    float4 s0 = *reinterpret_cast<float4*>(&zs[0][lr][u4]);
    float4 s1 = *reinterpret_cast<float4*>(&zs[1][lr][u4]);
    float4 s2 = *reinterpret_cast<float4*>(&zs[2][lr][u4]);
    float4 s3 = *reinterpret_cast<float4*>(&zs[3][lr][u4]);
    const float4 bb = *reinterpret_cast<const float4*>(&bd[gu]);
    float4 r;
    r.x = s0.x + s1.x + s2.x + s3.x + bb.x;
    r.y = s0.y + s1.y + s2.y + s3.y + bb.y;
    r.z = s0.z + s1.z + s2.z + s3.z + bb.z;
    r.w = s0.w + s1.w + s2.w + s3.w + bb.w;
    r.x = r.x > 0.f ? r.x : 0.f;
    r.y = r.y > 0.f ? r.y : 0.f;
    r.z = r.z > 0.f ? r.z : 0.f;
    r.w = r.w > 0.f ? r.w : 0.f;
    *reinterpret_cast<float4*>(&y[(size_t)grow * U_ + gu]) = r;
}

// ---------------- out[b] = sigmoid(y[b,:] @ Wo + bo) ----------------
__global__ __launch_bounds__(256)
void head2(const float* __restrict__ y, const float* __restrict__ Wo,
           const float* __restrict__ bo, float* __restrict__ out) {
    __shared__ float red[256];
    const int b = blockIdx.x;
    const int tid = threadIdx.x;
    float s = 0.f;
    for (int u = tid; u < U_; u += 256) s += y[(size_t)b * U_ + u] * Wo[u];
    red[tid] = s;
    __syncthreads();
    for (int off = 128; off > 0; off >>= 1) {
        if (tid < off) red[tid] += red[tid + off];
        __syncthreads();
    }
    if (tid == 0) out[b] = 1.f / (1.f + __expf(-(red[0] + bo[0])));
}

extern "C" void kernel_launch(void* const* d_in, const int* in_sizes, int n_in,
                              void* d_out, int out_size, void* d_ws, size_t ws_size,
                              hipStream_t stream) {
    const int*   tokens = (const int*)  d_in[0];
    const float* emb    = (const float*)d_in[1];
    const float* W0     = (const float*)d_in[2];
    const float* U0     = (const float*)d_in[3];
    const float* b0     = (const float*)d_in[4];
    const float* W1     = (const float*)d_in[5];
    const float* U1     = (const float*)d_in[6];
    const float* b1     = (const float*)d_in[7];
    const float* Wd     = (const float*)d_in[8];
    const float* bd     = (const float*)d_in[9];
    const float* Wo     = (const float*)d_in[10];
    const float* bo     = (const float*)d_in[11];

    // ws layout (bytes); requires ws_size >= ~120 MB
    char* base = (char*)d_ws;
    ushort* h0a = (ushort*)(base + 0);          //  512 KB
    ushort* h1a = (ushort*)(base + 524288);     //  512 KB
    float*  c0  = (float*) (base + 1048576);    // 1 MB
    float*  c1  = (float*) (base + 2097152);    // 1 MB
    ushort* h0b = (ushort*)(base + 3145728);
    ushort* h1b = (ushort*)(base + 3670016);
    float*  yb  = (float*) (base + 4194304);    // 1 MB
    ushort* Xbf = (ushort*)(base + 5242880);    // 2.5 MB
    ushort* W0p = (ushort*)(base + 7864320);    // 2 MB
    ushort* U0p = (ushort*)(base + 9961472);    // 32 MB
    ushort* W1p = (ushort*)(base + 43515904);   // 32 MB
    ushort* U1p = (ushort*)(base + 77070336);   // 32 MB
    ushort* Wdp = (ushort*)(base + 110624768);  // 8 MB

    // zero h0a, h1a, c0, c1 (contiguous 3 MB)
    hipMemsetAsync(d_ws, 0, 3145728, stream);

    embed_bf16<<<(T_ * B_ * EP_ + 255) / 256, 256, 0, stream>>>(tokens, emb, Xbf);
    pack_w<<<512,  256, 0, stream>>>(W0, E_, G4_, 4, 4,  W0p);
    pack_w<<<8192, 256, 0, stream>>>(U0, U_, G4_, 4, 64, U0p);
    pack_w<<<8192, 256, 0, stream>>>(W1, U_, G4_, 4, 64, W1p);
    pack_w<<<8192, 256, 0, stream>>>(U1, U_, G4_, 4, 64, U1p);
    pack_w<<<2048, 256, 0, stream>>>(Wd, U_, U_,  1, 64, Wdp);

    for (int t = 0; t < T_; ++t) {
        const ushort* h0in  = (t & 1) ? h0b : h0a;
        ushort*       h0out = (t & 1) ? h0a : h0b;
        const ushort* h1in  = (t & 1) ? h1b : h1a;
        ushort*       h1out = (t & 1) ? h1a : h1b;
        lstm_step_mfma<<<256, 1024, 0, stream>>>(Xbf + (size_t)t * B_ * EP_, EP_, W0p, 4,
                                                 h0in, U_, U0p, 64, b0, c0, h0out);
        lstm_step_mfma<<<256, 1024, 0, stream>>>(h0out, U_, W1p, 64,
                                                 h1in, U_, U1p, 64, b1, c1, h1out);
    }
    // t=79 (odd) wrote the 'a' buffers
    head_mfma<<<256, 256, 0, stream>>>(h1a, Wdp, bd, yb);
    head2<<<B_, 256, 0, stream>>>(yb, Wo, bo, (float*)d_out);
}

// Round 4
// 3716.741 us; speedup vs baseline: 51.7613x; 2.1270x over previous
//
#include <hip/hip_runtime.h>
#include <hip/hip_bf16.h>
#include <cstdint>

#define B_   128
#define T_   80
#define E_   100
#define EP_  128     // E padded to multiple of 32
#define U_   2048
#define G4_  8192

typedef __attribute__((ext_vector_type(8))) short bf16x8;
typedef __attribute__((ext_vector_type(4))) float f32x4;

__device__ __forceinline__ ushort f2bf(float x) {
    __hip_bfloat16 h = __float2bfloat16(x);
    return *reinterpret_cast<ushort*>(&h);
}

// ---------------- embedding -> A-fragment-packed bf16 X ----------------
// Xp[((t*8 + mhmt)*4 + i)*512 + lane*8 + j] =
//   x[t][row = (mhmt>>2)*64 + (mhmt&3)*16 + (lane&15)][e = i*32 + (lane>>4)*8 + j]
__global__ __launch_bounds__(256)
void embed_pack(const int* __restrict__ tokens, const float* __restrict__ emb,
                ushort* __restrict__ Xp) {
    int gtid = blockIdx.x * 256 + threadIdx.x;   // one 8-ushort chunk each
    if (gtid >= T_ * 8 * 4 * 64) return;
    int lane = gtid & 63;
    int rest = gtid >> 6;
    int i    = rest & 3;  rest >>= 2;
    int mhmt = rest & 7;
    int t    = rest >> 3;
    int row  = (mhmt >> 2) * 64 + (mhmt & 3) * 16 + (lane & 15);
    int k0   = i * 32 + (lane >> 4) * 8;
    const float* erow = emb + (size_t)tokens[row * T_ + t] * E_;
    ushort v[8];
#pragma unroll
    for (int j = 0; j < 8; ++j) {
        int e = k0 + j;
        v[j] = f2bf(e < E_ ? erow[e] : 0.f);
    }
    *reinterpret_cast<uint4*>(Xp + (size_t)gtid * 8) = *reinterpret_cast<const uint4*>(v);
}

// ---------------- weight pack: fp32 [K][Ncols] -> bf16 MFMA B-frag layout
__global__ __launch_bounds__(256)
void pack_w(const float* __restrict__ W, int K, int Ncols, int NG, int KB,
            ushort* __restrict__ out) {
    int gtid = blockIdx.x * 256 + threadIdx.x;
    int lane = gtid & 63;
    int rest = gtid >> 6;
    int g = rest % NG; rest /= NG;
    int i = rest % KB;
    int ut = rest / KB;
    if (ut >= U_ / 16) return;
    int col = g * U_ + ut * 16 + (lane & 15);
    int k0 = i * 32 + (lane >> 4) * 8;
    ushort v[8];
#pragma unroll
    for (int j = 0; j < 8; ++j) {
        int k = k0 + j;
        v[j] = f2bf(k < K ? W[(size_t)k * Ncols + col] : 0.f);
    }
    *reinterpret_cast<uint4*>(out + (size_t)gtid * 8) = *reinterpret_cast<const uint4*>(v);
}

// ---------------- fused LSTM step, all operands fragment-packed -------------
// grid 256: blockIdx = mh*128 + ut. 16 waves: gate g = w>>2, K-quarter kq = w&3.
// A-frag address: Ap + ((mh*4 + mt)*kbA + i)*512 + lane*8   (1 KB coalesced)
// h_out written in the same packed layout (kb = 64) for the next consumer.
__global__ __launch_bounds__(1024)
void lstm_step_mfma(const ushort* __restrict__ A0p, int kb0,
                    const ushort* __restrict__ Wp0,
                    const ushort* __restrict__ A1p, int kb1,
                    const ushort* __restrict__ Wp1,
                    const float* __restrict__ bias,
                    float* __restrict__ c,
                    ushort* __restrict__ h_out /* packed */) {
    const int tid  = threadIdx.x;
    const int lane = tid & 63;
    const int w    = tid >> 6;     // 0..15
    const int g    = w >> 2;       // gate
    const int kq   = w & 3;        // K-quarter
    const int ut   = blockIdx.x & 127;
    const int mh   = blockIdx.x >> 7;

    const ushort* a0 = A0p + ((size_t)(mh * 4) * kb0) * 512 + lane * 8;
    const ushort* a1 = A1p + ((size_t)(mh * 4) * kb1) * 512 + lane * 8;
    const ushort* wp0 = Wp0 + ((size_t)(ut * kb0) * 4 + g) * 512 + lane * 8;
    const ushort* wp1 = Wp1 + ((size_t)(ut * kb1) * 4 + g) * 512 + lane * 8;

    f32x4 acc[4];
#pragma unroll
    for (int mt = 0; mt < 4; ++mt) acc[mt] = f32x4{0.f, 0.f, 0.f, 0.f};

    auto LOAD = [&](int i, bf16x8* a, bf16x8& b) {
        if (i < kb0) {
            b = *reinterpret_cast<const bf16x8*>(wp0 + (size_t)i * 2048);
#pragma unroll
            for (int mt = 0; mt < 4; ++mt)
                a[mt] = *reinterpret_cast<const bf16x8*>(a0 + (size_t)(mt * kb0 + i) * 512);
        } else {
            int ii = i - kb0;
            b = *reinterpret_cast<const bf16x8*>(wp1 + (size_t)ii * 2048);
#pragma unroll
            for (int mt = 0; mt < 4; ++mt)
                a[mt] = *reinterpret_cast<const bf16x8*>(a1 + (size_t)(mt * kb1 + ii) * 512);
        }
    };
#define MFMA4(aa, bb)                                                            \
    {                                                                            \
        _Pragma("unroll")                                                        \
        for (int mt = 0; mt < 4; ++mt)                                           \
            acc[mt] = __builtin_amdgcn_mfma_f32_16x16x32_bf16(aa[mt], bb, acc[mt], 0, 0, 0); \
    }

    const int KBt = kb0 + kb1;           // 68 or 128, divisible by 4
    const int KBq = KBt >> 2;
    const int beg = kq * KBq;
    const int end = beg + KBq;

    bf16x8 aA[4], bA, aB[4], bB;
    int i = beg;
    LOAD(i, aA, bA);
    for (; i + 1 < end; i += 2) {
        LOAD(i + 1, aB, bB);
        MFMA4(aA, bA);
        if (i + 2 < end) LOAD(i + 2, aA, bA);
        MFMA4(aB, bB);
    }
    if (i < end) MFMA4(aA, bA);
#undef MFMA4

    // partial-sum exchange: zs[w][row_local][unit_local]
    __shared__ float zs[16][64][16];   // 64 KB
#pragma unroll
    for (int mt = 0; mt < 4; ++mt)
#pragma unroll
        for (int r = 0; r < 4; ++r)
            zs[w][mt * 16 + (lane >> 4) * 4 + r][lane & 15] = acc[mt][r];
    __syncthreads();

    // epilogue: tid -> (mt, lhg, cl, j); one (row, unit) each, packed h write
    const int j   = tid & 7;
    const int cl  = (tid >> 3) & 15;
    const int lhg = (tid >> 7) & 1;
    const int mt  = tid >> 8;
    const int ulocal = lhg * 8 + j;          // 0..15
    const int lr     = mt * 16 + cl;         // 0..63
    const int grow   = mh * 64 + lr;
    const int unit   = ut * 16 + ulocal;

    float zi = zs[0][lr][ulocal] + zs[1][lr][ulocal] + zs[2][lr][ulocal] + zs[3][lr][ulocal];
    float zf = zs[4][lr][ulocal] + zs[5][lr][ulocal] + zs[6][lr][ulocal] + zs[7][lr][ulocal];
    float zg = zs[8][lr][ulocal] + zs[9][lr][ulocal] + zs[10][lr][ulocal] + zs[11][lr][ulocal];
    float zo = zs[12][lr][ulocal] + zs[13][lr][ulocal] + zs[14][lr][ulocal] + zs[15][lr][ulocal];

    zi += bias[unit];
    zf += bias[U_ + unit];
    zg += bias[2 * U_ + unit];
    zo += bias[3 * U_ + unit];

    float si = 1.f / (1.f + __expf(-zi));
    float sf = 1.f / (1.f + __expf(-zf));
    float so = 1.f / (1.f + __expf(-zo));
    float tg = tanhf(zg);
    float cc = sf * c[(size_t)grow * U_ + unit] + si * tg;
    c[(size_t)grow * U_ + unit] = cc;

    // packed h_out: frag fi = (mh*4+mt)*64 + (unit>>5); pos = ((unit>>3)&3)*16+cl, j
    const int fi = (mh * 4 + mt) * 64 + (unit >> 5);
    const int lp = ((unit >> 3) & 3) * 16 + cl;
    h_out[(size_t)fi * 512 + lp * 8 + j] = f2bf(so * tanhf(cc));
}

// ---------------- head: y = relu(h1 @ Wd + bd); h1 is fragment-packed -------
__global__ __launch_bounds__(256)
void head_mfma(const ushort* __restrict__ h1p, const ushort* __restrict__ Wdp,
               const float* __restrict__ bd, float* __restrict__ y) {
    const int lane = threadIdx.x & 63;
    const int w    = threadIdx.x >> 6;  // k-split wave
    const int ut   = blockIdx.x & 127;
    const int mh   = blockIdx.x >> 7;

    const ushort* ap = h1p + ((size_t)(mh * 4) * 64) * 512 + lane * 8;
    const ushort* wp = Wdp + (size_t)(ut * 64 + w * 16) * 512 + lane * 8;

    f32x4 acc[4];
#pragma unroll
    for (int mt = 0; mt < 4; ++mt) acc[mt] = f32x4{0.f, 0.f, 0.f, 0.f};

    auto LOADH = [&](int i, bf16x8* a, bf16x8& b) {
        b = *reinterpret_cast<const bf16x8*>(wp + (size_t)i * 512);
        int kb = w * 16 + i;
#pragma unroll
        for (int mt = 0; mt < 4; ++mt)
            a[mt] = *reinterpret_cast<const bf16x8*>(ap + (size_t)(mt * 64 + kb) * 512);
    };

    bf16x8 aA[4], bA, aB[4], bB;
    LOADH(0, aA, bA);
    for (int i = 0; i < 16; i += 2) {
        LOADH(i + 1, aB, bB);
#pragma unroll
        for (int mt = 0; mt < 4; ++mt)
            acc[mt] = __builtin_amdgcn_mfma_f32_16x16x32_bf16(aA[mt], bA, acc[mt], 0, 0, 0);
        if (i + 2 < 16) LOADH(i + 2, aA, bA);
#pragma unroll
        for (int mt = 0; mt < 4; ++mt)
            acc[mt] = __builtin_amdgcn_mfma_f32_16x16x32_bf16(aB[mt], bB, acc[mt], 0, 0, 0);
    }

    __shared__ float zs[4][64][16];
#pragma unroll
    for (int mt = 0; mt < 4; ++mt)
#pragma unroll
        for (int r = 0; r < 4; ++r)
            zs[w][mt * 16 + (lane >> 4) * 4 + r][lane & 15] = acc[mt][r];
    __syncthreads();

    const int tid = threadIdx.x;
    const int lr  = tid >> 2;
    const int u4  = (tid & 3) * 4;
    const int grow = mh * 64 + lr;
    const int gu   = ut * 16 + u4;

    float4 s0 = *reinterpret_cast<float4*>(&zs[0][lr][u4]);
    float4 s1 = *reinterpret_cast<float4*>(&zs[1][lr][u4]);
    float4 s2 = *reinterpret_cast<float4*>(&zs[2][lr][u4]);
    float4 s3 = *reinterpret_cast<float4*>(&zs[3][lr][u4]);
    const float4 bb = *reinterpret_cast<const float4*>(&bd[gu]);
    float4 r;
    r.x = s0.x + s1.x + s2.x + s3.x + bb.x;
    r.y = s0.y + s1.y + s2.y + s3.y + bb.y;
    r.z = s0.z + s1.z + s2.z + s3.z + bb.z;
    r.w = s0.w + s1.w + s2.w + s3.w + bb.w;
    r.x = r.x > 0.f ? r.x : 0.f;
    r.y = r.y > 0.f ? r.y : 0.f;
    r.z = r.z > 0.f ? r.z : 0.f;
    r.w = r.w > 0.f ? r.w : 0.f;
    *reinterpret_cast<float4*>(&y[(size_t)grow * U_ + gu]) = r;
}

// ---------------- out[b] = sigmoid(y[b,:] @ Wo + bo) ----------------
__global__ __launch_bounds__(256)
void head2(const float* __restrict__ y, const float* __restrict__ Wo,
           const float* __restrict__ bo, float* __restrict__ out) {
    __shared__ float red[256];
    const int b = blockIdx.x;
    const int tid = threadIdx.x;
    float s = 0.f;
    for (int u = tid; u < U_; u += 256) s += y[(size_t)b * U_ + u] * Wo[u];
    red[tid] = s;
    __syncthreads();
    for (int off = 128; off > 0; off >>= 1) {
        if (tid < off) red[tid] += red[tid + off];
        __syncthreads();
    }
    if (tid == 0) out[b] = 1.f / (1.f + __expf(-(red[0] + bo[0])));
}

extern "C" void kernel_launch(void* const* d_in, const int* in_sizes, int n_in,
                              void* d_out, int out_size, void* d_ws, size_t ws_size,
                              hipStream_t stream) {
    const int*   tokens = (const int*)  d_in[0];
    const float* emb    = (const float*)d_in[1];
    const float* W0     = (const float*)d_in[2];
    const float* U0     = (const float*)d_in[3];
    const float* b0     = (const float*)d_in[4];
    const float* W1     = (const float*)d_in[5];
    const float* U1     = (const float*)d_in[6];
    const float* b1     = (const float*)d_in[7];
    const float* Wd     = (const float*)d_in[8];
    const float* bd     = (const float*)d_in[9];
    const float* Wo     = (const float*)d_in[10];
    const float* bo     = (const float*)d_in[11];

    // ws layout (bytes)
    char* base = (char*)d_ws;
    ushort* h0a = (ushort*)(base + 0);          //  512 KB (packed)
    ushort* h1a = (ushort*)(base + 524288);     //  512 KB (packed)
    float*  c0  = (float*) (base + 1048576);    // 1 MB
    float*  c1  = (float*) (base + 2097152);    // 1 MB
    ushort* h0b = (ushort*)(base + 3145728);
    ushort* h1b = (ushort*)(base + 3670016);
    float*  yb  = (float*) (base + 4194304);    // 1 MB
    ushort* Xp  = (ushort*)(base + 5242880);    // 2.62 MB (packed)
    ushort* W0p = (ushort*)(base + 7864320);    // 2 MB
    ushort* U0p = (ushort*)(base + 9961472);    // 32 MB
    ushort* W1p = (ushort*)(base + 43515904);   // 32 MB
    ushort* U1p = (ushort*)(base + 77070336);   // 32 MB
    ushort* Wdp = (ushort*)(base + 110624768);  // 8 MB

    // zero h0a, h1a, c0, c1 (contiguous 3 MB)
    hipMemsetAsync(d_ws, 0, 3145728, stream);

    embed_pack<<<(T_ * 8 * 4 * 64 + 255) / 256, 256, 0, stream>>>(tokens, emb, Xp);
    pack_w<<<512,  256, 0, stream>>>(W0, E_, G4_, 4, 4,  W0p);
    pack_w<<<8192, 256, 0, stream>>>(U0, U_, G4_, 4, 64, U0p);
    pack_w<<<8192, 256, 0, stream>>>(W1, U_, G4_, 4, 64, W1p);
    pack_w<<<8192, 256, 0, stream>>>(U1, U_, G4_, 4, 64, U1p);
    pack_w<<<2048, 256, 0, stream>>>(Wd, U_, U_,  1, 64, Wdp);

    for (int t = 0; t < T_; ++t) {
        const ushort* h0in  = (t & 1) ? h0b : h0a;
        ushort*       h0out = (t & 1) ? h0a : h0b;
        const ushort* h1in  = (t & 1) ? h1b : h1a;
        ushort*       h1out = (t & 1) ? h1a : h1b;
        lstm_step_mfma<<<256, 1024, 0, stream>>>(Xp + (size_t)t * 8 * 4 * 512, 4, W0p,
                                                 h0in, 64, U0p, b0, c0, h0out);
        lstm_step_mfma<<<256, 1024, 0, stream>>>(h0out, 64, W1p,
                                                 h1in, 64, U1p, b1, c1, h1out);
    }
    // t=79 (odd) wrote the 'a' buffers
    head_mfma<<<256, 256, 0, stream>>>(h1a, Wdp, bd, yb);
    head2<<<B_, 256, 0, stream>>>(yb, Wo, bo, (float*)d_out);
}

// Round 5
// 2489.867 us; speedup vs baseline: 77.2666x; 1.4927x over previous
//
#include <hip/hip_runtime.h>
#include <hip/hip_bf16.h>
#include <cstdint>

#define B_   128
#define T_   80
#define E_   100
#define U_   2048
#define G4_  8192

typedef __attribute__((ext_vector_type(8))) short bf16x8;
typedef __attribute__((ext_vector_type(4))) float f32x4;

__device__ __forceinline__ ushort f2bf(float x) {
    __hip_bfloat16 h = __float2bfloat16(x);
    return *reinterpret_cast<ushort*>(&h);
}

// ---------------- embedding -> A-fragment-packed bf16 X (kb0 = 8 frags) -----
// Xp[((t*8 + mtg)*8 + i)*512 + lane*8 + j] =
//   x[t][row=(mtg>>2)*64+(mtg&3)*16+(lane&15)][e = i*32 + (lane>>4)*8 + j]
__global__ __launch_bounds__(256)
void embed_pack(const int* __restrict__ tokens, const float* __restrict__ emb,
                ushort* __restrict__ Xp) {
    int gtid = blockIdx.x * 256 + threadIdx.x;   // one 8-ushort chunk each
    if (gtid >= T_ * 8 * 8 * 64) return;
    int lane = gtid & 63;
    int rest = gtid >> 6;
    int i    = rest & 7;  rest >>= 3;
    int mtg  = rest & 7;
    int t    = rest >> 3;
    int row  = (mtg >> 2) * 64 + (mtg & 3) * 16 + (lane & 15);
    int k0   = i * 32 + (lane >> 4) * 8;
    const float* erow = emb + (size_t)tokens[row * T_ + t] * E_;
    ushort v[8];
#pragma unroll
    for (int j = 0; j < 8; ++j) {
        int e = k0 + j;
        v[j] = f2bf(e < E_ ? erow[e] : 0.f);
    }
    *reinterpret_cast<uint4*>(Xp + (size_t)gtid * 8) = *reinterpret_cast<const uint4*>(v);
}

// ---------------- weight pack: fp32 [K][Ncols] -> bf16 MFMA B-frag layout ----
// out[(((ut*KB + i)*NG + g)*64 + lane)*8 + j] = W[k][g*U_ + ut*16 + (lane&15)]
__global__ __launch_bounds__(256)
void pack_w(const float* __restrict__ W, int K, int Ncols, int NG, int KB,
            ushort* __restrict__ out) {
    int gtid = blockIdx.x * 256 + threadIdx.x;
    int lane = gtid & 63;
    int rest = gtid >> 6;
    int g = rest % NG; rest /= NG;
    int i = rest % KB;
    int ut = rest / KB;
    if (ut >= U_ / 16) return;
    int col = g * U_ + ut * 16 + (lane & 15);
    int k0 = i * 32 + (lane >> 4) * 8;
    ushort v[8];
#pragma unroll
    for (int j = 0; j < 8; ++j) {
        int k = k0 + j;
        v[j] = f2bf(k < K ? W[(size_t)k * Ncols + col] : 0.f);
    }
    *reinterpret_cast<uint4*>(out + (size_t)gtid * 8) = *reinterpret_cast<const uint4*>(v);
}

// ---------------- fused LSTM step, wave = K-eighth, all 4 gates per wave -----
// grid 256 = mh(2) x ut(128); block 512 thr = 8 waves (kq 0..7).
// Each wave: 16 MFMA/iter (4 gates x 4 row-frags) over its K-eighth.
// No redundant loads: each A-frag and B-frag touched once per block.
__global__ __launch_bounds__(512)
void lstm_step_mfma(const ushort* __restrict__ A0p, int kb0,
                    const ushort* __restrict__ Wp0,
                    const ushort* __restrict__ A1p, int kb1,
                    const ushort* __restrict__ Wp1,
                    const float* __restrict__ bias,
                    float* __restrict__ c,
                    ushort* __restrict__ h_out /* packed */) {
    const int tid  = threadIdx.x;
    const int lane = tid & 63;
    const int kq   = tid >> 6;     // 0..7
    const int ut   = blockIdx.x & 127;
    const int mh   = blockIdx.x >> 7;

    const ushort* a0 = A0p + ((size_t)(mh * 4) * kb0) * 512 + lane * 8;
    const ushort* a1 = A1p + ((size_t)(mh * 4) * kb1) * 512 + lane * 8;
    const ushort* w0 = Wp0 + ((size_t)(ut * kb0) * 4) * 512 + lane * 8;
    const ushort* w1 = Wp1 + ((size_t)(ut * kb1) * 4) * 512 + lane * 8;

    f32x4 acc[4][4];   // [gate][mt]
#pragma unroll
    for (int g = 0; g < 4; ++g)
#pragma unroll
        for (int mt = 0; mt < 4; ++mt) acc[g][mt] = f32x4{0.f, 0.f, 0.f, 0.f};

    auto LOAD = [&](int i, bf16x8* a, bf16x8* b) {
        if (i < kb0) {
#pragma unroll
            for (int mt = 0; mt < 4; ++mt)
                a[mt] = *reinterpret_cast<const bf16x8*>(a0 + (size_t)(mt * kb0 + i) * 512);
#pragma unroll
            for (int g = 0; g < 4; ++g)
                b[g] = *reinterpret_cast<const bf16x8*>(w0 + (size_t)(i * 4 + g) * 512);
        } else {
            int ii = i - kb0;
#pragma unroll
            for (int mt = 0; mt < 4; ++mt)
                a[mt] = *reinterpret_cast<const bf16x8*>(a1 + (size_t)(mt * kb1 + ii) * 512);
#pragma unroll
            for (int g = 0; g < 4; ++g)
                b[g] = *reinterpret_cast<const bf16x8*>(w1 + (size_t)(ii * 4 + g) * 512);
        }
    };
#define MFMA_ALL(aa, bb)                                                         \
    {                                                                            \
        _Pragma("unroll")                                                        \
        for (int g = 0; g < 4; ++g)                                              \
            _Pragma("unroll")                                                    \
            for (int mt = 0; mt < 4; ++mt)                                       \
                acc[g][mt] = __builtin_amdgcn_mfma_f32_16x16x32_bf16(            \
                    aa[mt], bb[g], acc[g][mt], 0, 0, 0);                         \
    }

    const int KBt = kb0 + kb1;        // 72 or 128 (divisible by 8)
    const int KBq = KBt >> 3;
    const int beg = kq * KBq;
    const int end = beg + KBq;

    bf16x8 aA[4], bA[4], aB[4], bB[4];
    int i = beg;
    LOAD(i, aA, bA);
    for (; i + 1 < end; i += 2) {
        LOAD(i + 1, aB, bB);
        MFMA_ALL(aA, bA);
        if (i + 2 < end) LOAD(i + 2, aA, bA);
        MFMA_ALL(aB, bB);
    }
    if (i < end) MFMA_ALL(aA, bA);
#undef MFMA_ALL

    // kq-partial reduction, one gate at a time through a 32KB LDS buffer
    __shared__ float zs[8][64][16];
    const int lr = tid >> 3;          // 0..63
    const int u0 = (tid & 7) * 2;     // 0,2,..,14
    float zg2[4][2];
#pragma unroll
    for (int g = 0; g < 4; ++g) {
        __syncthreads();
#pragma unroll
        for (int mt = 0; mt < 4; ++mt)
#pragma unroll
            for (int r = 0; r < 4; ++r)
                zs[kq][mt * 16 + (lane >> 4) * 4 + r][lane & 15] = acc[g][mt][r];
        __syncthreads();
        float s0 = 0.f, s1 = 0.f;
#pragma unroll
        for (int w8 = 0; w8 < 8; ++w8) {
            s0 += zs[w8][lr][u0];
            s1 += zs[w8][lr][u0 + 1];
        }
        zg2[g][0] = s0;
        zg2[g][1] = s1;
    }

    // fused cell update for 2 units
    const int grow = mh * 64 + lr;
    const int unit = ut * 16 + u0;
    const float2 bi  = *reinterpret_cast<const float2*>(&bias[unit]);
    const float2 bfv = *reinterpret_cast<const float2*>(&bias[U_ + unit]);
    const float2 bgv = *reinterpret_cast<const float2*>(&bias[2 * U_ + unit]);
    const float2 bov = *reinterpret_cast<const float2*>(&bias[3 * U_ + unit]);
    float2 cv = *reinterpret_cast<float2*>(&c[(size_t)grow * U_ + unit]);

    float cn[2];
    ushort hv[2];
#pragma unroll
    for (int e = 0; e < 2; ++e) {
        float zi = zg2[0][e] + (e ? bi.y : bi.x);
        float zf = zg2[1][e] + (e ? bfv.y : bfv.x);
        float zg = zg2[2][e] + (e ? bgv.y : bgv.x);
        float zo = zg2[3][e] + (e ? bov.y : bov.x);
        float si = 1.f / (1.f + __expf(-zi));
        float sf = 1.f / (1.f + __expf(-zf));
        float so = 1.f / (1.f + __expf(-zo));
        float tg = tanhf(zg);
        float cc = sf * (e ? cv.y : cv.x) + si * tg;
        cn[e] = cc;
        hv[e] = f2bf(so * tanhf(cc));
    }
    *reinterpret_cast<float2*>(&c[(size_t)grow * U_ + unit]) = make_float2(cn[0], cn[1]);

    // packed h write (same layout as A-frags with kb=64)
    const int mt = lr >> 4;
    const int cl = lr & 15;
    const int fi = (mh * 4 + mt) * 64 + (unit >> 5);
    const int lp = ((unit >> 3) & 3) * 16 + cl;
    *reinterpret_cast<ushort2*>(&h_out[(size_t)fi * 512 + lp * 8 + (unit & 7)]) =
        make_ushort2(hv[0], hv[1]);
}

// ---------------- head: y = relu(h1 @ Wd + bd); h1 is fragment-packed -------
__global__ __launch_bounds__(256)
void head_mfma(const ushort* __restrict__ h1p, const ushort* __restrict__ Wdp,
               const float* __restrict__ bd, float* __restrict__ y) {
    const int lane = threadIdx.x & 63;
    const int w    = threadIdx.x >> 6;  // k-split wave
    const int ut   = blockIdx.x & 127;
    const int mh   = blockIdx.x >> 7;

    const ushort* ap = h1p + ((size_t)(mh * 4) * 64) * 512 + lane * 8;
    const ushort* wp = Wdp + (size_t)(ut * 64 + w * 16) * 512 + lane * 8;

    f32x4 acc[4];
#pragma unroll
    for (int mt = 0; mt < 4; ++mt) acc[mt] = f32x4{0.f, 0.f, 0.f, 0.f};

    auto LOADH = [&](int i, bf16x8* a, bf16x8& b) {
        b = *reinterpret_cast<const bf16x8*>(wp + (size_t)i * 512);
        int kb = w * 16 + i;
#pragma unroll
        for (int mt = 0; mt < 4; ++mt)
            a[mt] = *reinterpret_cast<const bf16x8*>(ap + (size_t)(mt * 64 + kb) * 512);
    };

    bf16x8 aA[4], bA, aB[4], bB;
    LOADH(0, aA, bA);
    for (int i = 0; i < 16; i += 2) {
        LOADH(i + 1, aB, bB);
#pragma unroll
        for (int mt = 0; mt < 4; ++mt)
            acc[mt] = __builtin_amdgcn_mfma_f32_16x16x32_bf16(aA[mt], bA, acc[mt], 0, 0, 0);
        if (i + 2 < 16) LOADH(i + 2, aA, bA);
#pragma unroll
        for (int mt = 0; mt < 4; ++mt)
            acc[mt] = __builtin_amdgcn_mfma_f32_16x16x32_bf16(aB[mt], bB, acc[mt], 0, 0, 0);
    }

    __shared__ float zs[4][64][16];
#pragma unroll
    for (int mt = 0; mt < 4; ++mt)
#pragma unroll
        for (int r = 0; r < 4; ++r)
            zs[w][mt * 16 + (lane >> 4) * 4 + r][lane & 15] = acc[mt][r];
    __syncthreads();

    const int tid = threadIdx.x;
    const int lr  = tid >> 2;
    const int u4  = (tid & 3) * 4;
    const int grow = mh * 64 + lr;
    const int gu   = ut * 16 + u4;

    float4 s0 = *reinterpret_cast<float4*>(&zs[0][lr][u4]);
    float4 s1 = *reinterpret_cast<float4*>(&zs[1][lr][u4]);
    float4 s2 = *reinterpret_cast<float4*>(&zs[2][lr][u4]);
    float4 s3 = *reinterpret_cast<float4*>(&zs[3][lr][u4]);
    const float4 bb = *reinterpret_cast<const float4*>(&bd[gu]);
    float4 r;
    r.x = s0.x + s1.x + s2.x + s3.x + bb.x;
    r.y = s0.y + s1.y + s2.y + s3.y + bb.y;
    r.z = s0.z + s1.z + s2.z + s3.z + bb.z;
    r.w = s0.w + s1.w + s2.w + s3.w + bb.w;
    r.x = r.x > 0.f ? r.x : 0.f;
    r.y = r.y > 0.f ? r.y : 0.f;
    r.z = r.z > 0.f ? r.z : 0.f;
    r.w = r.w > 0.f ? r.w : 0.f;
    *reinterpret_cast<float4*>(&y[(size_t)grow * U_ + gu]) = r;
}

// ---------------- out[b] = sigmoid(y[b,:] @ Wo + bo) ----------------
__global__ __launch_bounds__(256)
void head2(const float* __restrict__ y, const float* __restrict__ Wo,
           const float* __restrict__ bo, float* __restrict__ out) {
    __shared__ float red[256];
    const int b = blockIdx.x;
    const int tid = threadIdx.x;
    float s = 0.f;
    for (int u = tid; u < U_; u += 256) s += y[(size_t)b * U_ + u] * Wo[u];
    red[tid] = s;
    __syncthreads();
    for (int off = 128; off > 0; off >>= 1) {
        if (tid < off) red[tid] += red[tid + off];
        __syncthreads();
    }
    if (tid == 0) out[b] = 1.f / (1.f + __expf(-(red[0] + bo[0])));
}

extern "C" void kernel_launch(void* const* d_in, const int* in_sizes, int n_in,
                              void* d_out, int out_size, void* d_ws, size_t ws_size,
                              hipStream_t stream) {
    const int*   tokens = (const int*)  d_in[0];
    const float* emb    = (const float*)d_in[1];
    const float* W0     = (const float*)d_in[2];
    const float* U0     = (const float*)d_in[3];
    const float* b0     = (const float*)d_in[4];
    const float* W1     = (const float*)d_in[5];
    const float* U1     = (const float*)d_in[6];
    const float* b1     = (const float*)d_in[7];
    const float* Wd     = (const float*)d_in[8];
    const float* bd     = (const float*)d_in[9];
    const float* Wo     = (const float*)d_in[10];
    const float* bo     = (const float*)d_in[11];

    // ws layout (bytes); total ~117 MB
    char* base = (char*)d_ws;
    ushort* h0a = (ushort*)(base + 0);          //  512 KB (packed)
    ushort* h1a = (ushort*)(base + 524288);     //  512 KB (packed)
    float*  c0  = (float*) (base + 1048576);    // 1 MB
    float*  c1  = (float*) (base + 2097152);    // 1 MB
    ushort* h0b = (ushort*)(base + 3145728);
    ushort* h1b = (ushort*)(base + 3670016);
    ushort* Xp  = (ushort*)(base + 4194304);    // 5 MB (packed, kb0=8)
    float*  yb  = (float*) (base + 4194304);    // overlays Xp (Xp dead by head)
    ushort* W0p = (ushort*)(base + 9437184);    // 4 MB
    ushort* U0p = (ushort*)(base + 13631488);   // 32 MB
    ushort* W1p = (ushort*)(base + 47185920);   // 32 MB
    ushort* U1p = (ushort*)(base + 80740352);   // 32 MB
    ushort* Wdp = (ushort*)(base + 114294784);  // 8 MB

    // zero h0a, h1a, c0, c1 (contiguous 3 MB)
    hipMemsetAsync(d_ws, 0, 3145728, stream);

    embed_pack<<<(T_ * 8 * 8 * 64 + 255) / 256, 256, 0, stream>>>(tokens, emb, Xp);
    pack_w<<<1024, 256, 0, stream>>>(W0, E_, G4_, 4, 8,  W0p);
    pack_w<<<8192, 256, 0, stream>>>(U0, U_, G4_, 4, 64, U0p);
    pack_w<<<8192, 256, 0, stream>>>(W1, U_, G4_, 4, 64, W1p);
    pack_w<<<8192, 256, 0, stream>>>(U1, U_, G4_, 4, 64, U1p);
    pack_w<<<2048, 256, 0, stream>>>(Wd, U_, U_,  1, 64, Wdp);

    for (int t = 0; t < T_; ++t) {
        const ushort* h0in  = (t & 1) ? h0b : h0a;
        ushort*       h0out = (t & 1) ? h0a : h0b;
        const ushort* h1in  = (t & 1) ? h1b : h1a;
        ushort*       h1out = (t & 1) ? h1a : h1b;
        lstm_step_mfma<<<256, 512, 0, stream>>>(Xp + (size_t)t * 8 * 8 * 512, 8, W0p,
                                                h0in, 64, U0p, b0, c0, h0out);
        lstm_step_mfma<<<256, 512, 0, stream>>>(h0out, 64, W1p,
                                                h1in, 64, U1p, b1, c1, h1out);
    }
    // t=79 (odd) wrote the 'a' buffers
    head_mfma<<<256, 256, 0, stream>>>(h1a, Wdp, bd, yb);
    head2<<<B_, 256, 0, stream>>>(yb, Wo, bo, (float*)d_out);
}